// Round 1
// baseline (574.401 us; speedup 1.0000x reference)
//
#include <hip/hip_runtime.h>
#include <math.h>

#define DEV __device__ __forceinline__

typedef unsigned short u16;
typedef unsigned int   u32;
typedef __bf16 bf16x8 __attribute__((ext_vector_type(8)));
typedef float  f32x4  __attribute__((ext_vector_type(4)));
typedef u16    u16x8  __attribute__((ext_vector_type(8)));
typedef u16    u16x4  __attribute__((ext_vector_type(4)));

// ---------- helpers ----------
DEV u16 f2b(float f) {                 // f32 -> bf16 RNE
  u32 u = __builtin_bit_cast(u32, f);
  u = (u + 0x7FFFu + ((u >> 16) & 1u)) >> 16;
  return (u16)u;
}
DEV float b2f(u16 h) { u32 u = (u32)h << 16; return __builtin_bit_cast(float, u); }

DEV void gl_lds16(const u16* g, u16* l) {  // async global->LDS, 16B/lane
  __builtin_amdgcn_global_load_lds((const __attribute__((address_space(1))) void*)g,
                                   (__attribute__((address_space(3))) void*)l, 16, 0, 0);
}

DEV float wred_max(float v) {
#pragma unroll
  for (int o = 32; o > 0; o >>= 1) v = fmaxf(v, __shfl_xor(v, o, 64));
  return v;
}
DEV float wred_sum(float v) {
#pragma unroll
  for (int o = 32; o > 0; o >>= 1) v += __shfl_xor(v, o, 64);
  return v;
}

// ---------- concat emb1|emb2 and convert to bf16 ----------
__global__ __launch_bounds__(256) void concat_convert(
    const float* __restrict__ e1, const float* __restrict__ e2, u16* __restrict__ xb) {
  const size_t idx = ((size_t)blockIdx.x * 256 + threadIdx.x) * 8;  // 8 elems/thread
  const int d = (int)(idx & 1023);
  const size_t row = idx >> 10;
  const float* s = (d < 512) ? (e1 + row * 512 + d) : (e2 + row * 512 + (d - 512));
  f32x4 a = *(const f32x4*)s;
  f32x4 b = *(const f32x4*)(s + 4);
  u16x8 o;
  o[0]=f2b(a[0]); o[1]=f2b(a[1]); o[2]=f2b(a[2]); o[3]=f2b(a[3]);
  o[4]=f2b(b[0]); o[5]=f2b(b[1]); o[6]=f2b(b[2]); o[7]=f2b(b[3]);
  *(u16x8*)(xb + idx) = o;
}

// ---------- transpose f32 [K][N] -> bf16 [N][K] (weights) ----------
__global__ __launch_bounds__(256) void transpose_w(
    const float* __restrict__ W, int ldi, u16* __restrict__ WT, int ldo) {
  __shared__ float tile[64][65];
  const int tx = threadIdx.x & 63, ty = threadIdx.x >> 6;
  const int r0 = blockIdx.y * 64, c0 = blockIdx.x * 64;
#pragma unroll
  for (int i = 0; i < 16; ++i)
    tile[ty + 4*i][tx] = W[(size_t)(r0 + ty + 4*i) * ldi + c0 + tx];
  __syncthreads();
#pragma unroll
  for (int i = 0; i < 16; ++i)
    WT[(size_t)(c0 + ty + 4*i) * ldo + r0 + tx] = f2b(tile[tx][ty + 4*i]);
}

// ---------- transpose bf16 [R][C] -> bf16 [C][R], batched ----------
__global__ __launch_bounds__(256) void transpose_v(
    const u16* __restrict__ in, int ldi, long long si,
    u16* __restrict__ out, int ldo, long long so) {
  __shared__ u16 tile[64][65];
  in  += (size_t)blockIdx.z * (size_t)si;
  out += (size_t)blockIdx.z * (size_t)so;
  const int tx = threadIdx.x & 63, ty = threadIdx.x >> 6;
  const int r0 = blockIdx.y * 64, c0 = blockIdx.x * 64;
#pragma unroll
  for (int i = 0; i < 16; ++i)
    tile[ty + 4*i][tx] = in[(size_t)(r0 + ty + 4*i) * ldi + c0 + tx];
  __syncthreads();
#pragma unroll
  for (int i = 0; i < 16; ++i)
    out[(size_t)(c0 + ty + 4*i) * ldo + r0 + tx] = tile[tx][ty + 4*i];
}

// ---------- fused qkv bias ----------
__global__ void concat_bias(const float* __restrict__ bq, const float* __restrict__ bk,
                            const float* __restrict__ bv, float* __restrict__ o) {
  int i = blockIdx.x * 256 + threadIdx.x;  // 3072 total
  o[i] = (i < 1024) ? bq[i] : (i < 2048 ? bk[i - 1024] : bv[i - 2048]);
}

// ---------- bf16 GEMM: C[M,N] = act(scale * A[M,K] x B^T[N,K] + bias) ----------
// 128x128 tile, BK=32, 4 waves (2x2), 4x4 16x16x32 MFMA frags/wave (m97 structure)
template<int F32OUT, int RELU>
__global__ __launch_bounds__(256) void gemm_bt(
    const u16* __restrict__ A, int lda, long long sA,
    const u16* __restrict__ B, int ldb, long long sB,
    void* __restrict__ C, int ldc, long long sC,
    const float* __restrict__ bias, float scale, int K) {
  __shared__ __align__(16) u16 As[128 * 32];
  __shared__ __align__(16) u16 Bs[128 * 32];
  const int t = threadIdx.x;
  const int ln = t & 63, wv = t >> 6;
  const int m0 = blockIdx.y * 128, n0 = blockIdx.x * 128;
  const int bz = blockIdx.z;
  A += (size_t)bz * (size_t)sA;
  B += (size_t)bz * (size_t)sB;

  // staging map: chunk c covers tile elems [c*512, c*512+512); lane l -> 8 elems
  const int c0 = wv * 2, c1 = c0 + 1;
  const int eo0 = c0 * 512 + ln * 8;
  const int eo1 = eo0 + 512;
  const u16* gA0 = A + (size_t)(m0 + (eo0 >> 5)) * lda + (eo0 & 31);
  const u16* gA1 = A + (size_t)(m0 + (eo1 >> 5)) * lda + (eo1 & 31);
  const u16* gB0 = B + (size_t)(n0 + (eo0 >> 5)) * ldb + (eo0 & 31);
  const u16* gB1 = B + (size_t)(n0 + (eo1 >> 5)) * ldb + (eo1 & 31);
  u16* lA0 = &As[c0 * 512]; u16* lA1 = &As[c1 * 512];
  u16* lB0 = &Bs[c0 * 512]; u16* lB1 = &Bs[c1 * 512];

  const int wm = (wv >> 1) * 64, wn = (wv & 1) * 64;
  const int l15 = ln & 15, lhi = ln >> 4;

  f32x4 acc[4][4] = {};
  const int KT = K >> 5;
  for (int kt = 0; kt < KT; ++kt) {
    gl_lds16(gA0, lA0); gl_lds16(gA1, lA1);
    gl_lds16(gB0, lB0); gl_lds16(gB1, lB1);
    gA0 += 32; gA1 += 32; gB0 += 32; gB1 += 32;
    __syncthreads();  // drains vmcnt -> LDS tiles ready
    bf16x8 af[4], bfr[4];
#pragma unroll
    for (int i = 0; i < 4; ++i)
      af[i] = *(const bf16x8*)&As[(wm + i * 16 + l15) * 32 + lhi * 8];
#pragma unroll
    for (int i = 0; i < 4; ++i)
      bfr[i] = *(const bf16x8*)&Bs[(wn + i * 16 + l15) * 32 + lhi * 8];
#pragma unroll
    for (int i = 0; i < 4; ++i)
#pragma unroll
      for (int j = 0; j < 4; ++j)
        acc[i][j] = __builtin_amdgcn_mfma_f32_16x16x32_bf16(af[i], bfr[j], acc[i][j], 0, 0, 0);
    __syncthreads();
  }

  // epilogue: D row=(lhi*4+r), col=l15 within each 16x16 frag (m89-verified)
  const size_t cb = (size_t)bz * (size_t)sC;
#pragma unroll
  for (int i = 0; i < 4; ++i) {
    const int rg = m0 + wm + i * 16 + lhi * 4;
#pragma unroll
    for (int j = 0; j < 4; ++j) {
      const int cg = n0 + wn + j * 16 + l15;
      const float bsv = bias ? bias[cg] : 0.f;
#pragma unroll
      for (int r = 0; r < 4; ++r) {
        float v = acc[i][j][r] * scale + bsv;
        if (RELU) v = fmaxf(v, 0.f);
        if (F32OUT) ((float*)C)[cb + (size_t)(rg + r) * ldc + cg] = v;
        else        ((u16*)C)[cb + (size_t)(rg + r) * ldc + cg] = f2b(v);
      }
    }
  }
}

// ---------- row softmax with query-row mask, f32 scores -> bf16 attn ----------
__global__ __launch_bounds__(256) void softmax_mask(
    const float* __restrict__ sc, const int* __restrict__ m1,
    const int* __restrict__ m2, u16* __restrict__ attn) {
  __shared__ float red[8];
  const int row = blockIdx.x;            // b*1024 + q
  const int b = row >> 10, q = row & 1023;
  const int mk = (q < 512) ? m1[b * 512 + q] : m2[b * 512 + q - 512];
  f32x4 v = ((const f32x4*)(sc + (size_t)row * 1024))[threadIdx.x];
  if (mk == 0) { v[0] = v[1] = v[2] = v[3] = -INFINITY; }
  float mx = fmaxf(fmaxf(v[0], v[1]), fmaxf(v[2], v[3]));
  mx = wred_max(mx);
  const int ln = threadIdx.x & 63, wv = threadIdx.x >> 6;
  if (ln == 0) red[wv] = mx;
  __syncthreads();
  mx = fmaxf(fmaxf(red[0], red[1]), fmaxf(red[2], red[3]));
  float e0 = __expf(v[0] - mx), e1 = __expf(v[1] - mx);
  float e2 = __expf(v[2] - mx), e3 = __expf(v[3] - mx);
  float s = wred_sum(e0 + e1 + e2 + e3);
  if (ln == 0) red[4 + wv] = s;
  __syncthreads();
  const float inv = 1.f / (red[4] + red[5] + red[6] + red[7]);
  u16x4 o; o[0] = f2b(e0 * inv); o[1] = f2b(e1 * inv); o[2] = f2b(e2 * inv); o[3] = f2b(e3 * inv);
  *(u16x4*)(attn + (size_t)row * 1024 + threadIdx.x * 4) = o;
}

// ---------- final: sigmoid(h2 . W3 + b3), one wave per row ----------
__global__ __launch_bounds__(256) void logits_sigmoid(
    const u16* __restrict__ h2, const float* __restrict__ W3,
    const float* __restrict__ b3, float* __restrict__ out) {
  const int wid = (blockIdx.x * 256 + threadIdx.x) >> 6;  // row
  const int ln = threadIdx.x & 63;
  const u16* r = h2 + (size_t)wid * 1024 + ln * 16;
  u16x8 v0 = *(const u16x8*)r;
  u16x8 v1 = *(const u16x8*)(r + 8);
  const float* w = W3 + ln * 16;
  float s = 0.f;
#pragma unroll
  for (int i = 0; i < 8; ++i) s += b2f(v0[i]) * w[i];
#pragma unroll
  for (int i = 0; i < 8; ++i) s += b2f(v1[i]) * w[8 + i];
#pragma unroll
  for (int o = 32; o > 0; o >>= 1) s += __shfl_down(s, o, 64);
  if (ln == 0) out[wid] = 1.f / (1.f + __expf(-(s + b3[0])));
}

// ---------- launcher ----------
extern "C" void kernel_launch(void* const* d_in, const int* in_sizes, int n_in,
                              void* d_out, int out_size, void* d_ws, size_t ws_size,
                              hipStream_t stream) {
  (void)in_sizes; (void)n_in; (void)out_size; (void)ws_size;
  const float* emb1 = (const float*)d_in[0];
  const float* emb2 = (const float*)d_in[1];
  const int*   mask1 = (const int*)d_in[2];
  const int*   mask2 = (const int*)d_in[3];
  const float* Wq = (const float*)d_in[4];  const float* bq = (const float*)d_in[5];
  const float* Wk = (const float*)d_in[6];  const float* bk = (const float*)d_in[7];
  const float* Wv = (const float*)d_in[8];  const float* bv = (const float*)d_in[9];
  const float* W1 = (const float*)d_in[10]; const float* b1 = (const float*)d_in[11];
  const float* W2 = (const float*)d_in[12]; const float* b2 = (const float*)d_in[13];
  const float* W3 = (const float*)d_in[14]; const float* b3 = (const float*)d_in[15];

  // ws layout (bytes), hand-aliased; peak ~238 MiB
  char* ws = (char*)d_ws;
  u16*  QKV   = (u16*)(ws + 0);            // [16384][3072] bf16 (100.7MB); later h1/h2
  u16*  VT    = (u16*)(ws + 100663296);    // [16][1024][1024] bf16 (33.6MB)
  u16*  XB    = (u16*)(ws + 134217728);    // [16384][1024] bf16 (33.6MB); later attn
  u16*  WTQKV = (u16*)(ws + 167772160);    // [3072][1024] bf16 (6.3MB)
  u16*  W1T   = (u16*)(ws + 174063616);    // [2048][1024] bf16 (4.2MB)
  u16*  W2T   = (u16*)(ws + 178257920);    // [1024][2048] bf16 (4.2MB)
  float* SC   = (float*)(ws + 182452224);  // [16][1024][1024] f32 (67.1MB); later attended
  float* BF_  = (float*)(ws + 249561088);  // [3072] f32
  u16*  ATTN  = XB;                        // xb dead after QKV GEMM
  u16*  ATT   = (u16*)(ws + 182452224);    // scores dead after softmax
  u16*  H1    = (u16*)(ws + 0);            // QKV dead after PV
  u16*  H2    = (u16*)(ws + 67108864);
  float* out  = (float*)d_out;

  const float SCALE = 0.04419417382415922f;  // 1/sqrt(512)

  concat_convert<<<8192, 256, 0, stream>>>(emb1, emb2, XB);
  transpose_w<<<dim3(16, 16), 256, 0, stream>>>(Wq, 1024, WTQKV, 1024);
  transpose_w<<<dim3(16, 16), 256, 0, stream>>>(Wk, 1024, WTQKV + 1024 * 1024, 1024);
  transpose_w<<<dim3(16, 16), 256, 0, stream>>>(Wv, 1024, WTQKV + 2048 * 1024, 1024);
  transpose_w<<<dim3(32, 16), 256, 0, stream>>>(W1, 2048, W1T, 1024);
  transpose_w<<<dim3(16, 32), 256, 0, stream>>>(W2, 1024, W2T, 2048);
  concat_bias<<<12, 256, 0, stream>>>(bq, bk, bv, BF_);

  // QKV: [16384,1024] x [1024,3072] -> bf16 [16384,3072]
  gemm_bt<0, 0><<<dim3(24, 128, 1), 256, 0, stream>>>(
      XB, 1024, 0, WTQKV, 1024, 0, QKV, 3072, 0, BF_, 1.f, 1024);
  // V^T per batch: [S,D] -> [D,S]
  transpose_v<<<dim3(16, 16, 16), 256, 0, stream>>>(
      QKV + 2048, 3072, 3145728LL, VT, 1024, 1048576LL);
  // scores = scale * Q K^T : batched, f32 out
  gemm_bt<1, 0><<<dim3(8, 8, 16), 256, 0, stream>>>(
      QKV, 3072, 3145728LL, QKV + 1024, 3072, 3145728LL,
      SC, 1024, 1048576LL, nullptr, SCALE, 1024);
  softmax_mask<<<16384, 256, 0, stream>>>(SC, mask1, mask2, ATTN);
  // attended = attn @ V : batched
  gemm_bt<0, 0><<<dim3(8, 8, 16), 256, 0, stream>>>(
      ATTN, 1024, 1048576LL, VT, 1024, 1048576LL,
      ATT, 1024, 1048576LL, nullptr, 1.f, 1024);
  // MLP
  gemm_bt<0, 1><<<dim3(16, 128, 1), 256, 0, stream>>>(
      ATT, 1024, 0, W1T, 1024, 0, H1, 2048, 0, b1, 1.f, 1024);
  gemm_bt<0, 1><<<dim3(8, 128, 1), 256, 0, stream>>>(
      H1, 2048, 0, W2T, 2048, 0, H2, 1024, 0, b2, 1.f, 2048);
  logits_sigmoid<<<4096, 256, 0, stream>>>(H2, W3, b3, out);
}

// Round 2
// 430.970 us; speedup vs baseline: 1.3328x; 1.3328x over previous
//
#include <hip/hip_runtime.h>
#include <math.h>

#define DEV __device__ __forceinline__

typedef unsigned short u16;
typedef unsigned int   u32;
typedef __bf16 bf16x8 __attribute__((ext_vector_type(8)));
typedef float  f32x4  __attribute__((ext_vector_type(4)));
typedef u16    u16x8  __attribute__((ext_vector_type(8)));
typedef u16    u16x4  __attribute__((ext_vector_type(4)));

// ---------- helpers ----------
DEV u16 f2b(float f) {                 // f32 -> bf16 RNE
  u32 u = __builtin_bit_cast(u32, f);
  u = (u + 0x7FFFu + ((u >> 16) & 1u)) >> 16;
  return (u16)u;
}
DEV float b2f(u16 h) { u32 u = (u32)h << 16; return __builtin_bit_cast(float, u); }

DEV void gl_lds16(const u16* g, u16* l) {  // async global->LDS, 16B/lane (lds ptr wave-uniform)
  __builtin_amdgcn_global_load_lds((const __attribute__((address_space(1))) void*)g,
                                   (__attribute__((address_space(3))) void*)l, 16, 0, 0);
}

DEV float wred_max(float v) {
#pragma unroll
  for (int o = 32; o > 0; o >>= 1) v = fmaxf(v, __shfl_xor(v, o, 64));
  return v;
}
DEV float wred_sum(float v) {
#pragma unroll
  for (int o = 32; o > 0; o >>= 1) v += __shfl_xor(v, o, 64);
  return v;
}

// ---------- concat emb1|emb2 and convert to bf16 ----------
__global__ __launch_bounds__(256) void concat_convert(
    const float* __restrict__ e1, const float* __restrict__ e2, u16* __restrict__ xb) {
  const size_t idx = ((size_t)blockIdx.x * 256 + threadIdx.x) * 8;  // 8 elems/thread
  const int d = (int)(idx & 1023);
  const size_t row = idx >> 10;
  const float* s = (d < 512) ? (e1 + row * 512 + d) : (e2 + row * 512 + (d - 512));
  f32x4 a = *(const f32x4*)s;
  f32x4 b = *(const f32x4*)(s + 4);
  u16x8 o;
  o[0]=f2b(a[0]); o[1]=f2b(a[1]); o[2]=f2b(a[2]); o[3]=f2b(a[3]);
  o[4]=f2b(b[0]); o[5]=f2b(b[1]); o[6]=f2b(b[2]); o[7]=f2b(b[3]);
  *(u16x8*)(xb + idx) = o;
}

// ---------- transpose f32 [K][N] -> bf16 [N][K] (weights) ----------
__global__ __launch_bounds__(256) void transpose_w(
    const float* __restrict__ W, int ldi, u16* __restrict__ WT, int ldo) {
  __shared__ float tile[64][65];
  const int tx = threadIdx.x & 63, ty = threadIdx.x >> 6;
  const int r0 = blockIdx.y * 64, c0 = blockIdx.x * 64;
#pragma unroll
  for (int i = 0; i < 16; ++i)
    tile[ty + 4*i][tx] = W[(size_t)(r0 + ty + 4*i) * ldi + c0 + tx];
  __syncthreads();
#pragma unroll
  for (int i = 0; i < 16; ++i)
    WT[(size_t)(c0 + ty + 4*i) * ldo + r0 + tx] = f2b(tile[tx][ty + 4*i]);
}

// ---------- transpose bf16 [R][C] -> bf16 [C][R], batched ----------
__global__ __launch_bounds__(256) void transpose_v(
    const u16* __restrict__ in, int ldi, long long si,
    u16* __restrict__ out, int ldo, long long so) {
  __shared__ u16 tile[64][65];
  in  += (size_t)blockIdx.z * (size_t)si;
  out += (size_t)blockIdx.z * (size_t)so;
  const int tx = threadIdx.x & 63, ty = threadIdx.x >> 6;
  const int r0 = blockIdx.y * 64, c0 = blockIdx.x * 64;
#pragma unroll
  for (int i = 0; i < 16; ++i)
    tile[ty + 4*i][tx] = in[(size_t)(r0 + ty + 4*i) * ldi + c0 + tx];
  __syncthreads();
#pragma unroll
  for (int i = 0; i < 16; ++i)
    out[(size_t)(c0 + ty + 4*i) * ldo + r0 + tx] = tile[tx][ty + 4*i];
}

// ---------- fused qkv bias ----------
__global__ void concat_bias(const float* __restrict__ bq, const float* __restrict__ bk,
                            const float* __restrict__ bv, float* __restrict__ o) {
  int i = blockIdx.x * 256 + threadIdx.x;  // 3072 total
  o[i] = (i < 1024) ? bq[i] : (i < 2048 ? bk[i - 1024] : bv[i - 2048]);
}

// ============================================================================
// 256x256 8-phase-style bf16 GEMM: C = act(scale * A[M,K] x B^T[N,K] + bias)
// BK=32, 4 LDS buffers (4 x (A 16KB + B 16KB) = 128 KiB), stage tile t+3 while
// computing tile t -> counted vmcnt(8) (2 tiles in flight), never drain-0 in
// main loop. 8 waves (2Mx4N), per wave 128x64 out = 8x4 frags of 16x16,
// 2 phases/tile x 16 MFMA. LDS XOR swizzle: granule ^= (row>>1)&3 applied on
// pre-swizzled GLOBAL source (linear gl_lds dest) and on ds_read address
// -> 8 lanes/bank-group over 8 groups = conflict-free ds_read_b128.
// ============================================================================
template<int F32OUT, int RELU>
__global__ __launch_bounds__(512, 2) void gemm256(
    const u16* __restrict__ A, int lda, long long sA,
    const u16* __restrict__ B, int ldb, long long sB,
    void* __restrict__ C, int ldc, long long sC,
    const float* __restrict__ bias, float scale, int K, int swz_gy) {
  __shared__ __align__(16) u16 lds[4][2][8192];   // [buf][A/B][256 rows x 32 cols]

  const int t  = threadIdx.x;
  const int ln = t & 63, wv = t >> 6;

  // block-id mapping (+bijective XCD swizzle for 2D grids; all 2D grids %8==0)
  int bx, by;
  if (gridDim.z == 1) {
    const int flat = blockIdx.y * gridDim.x + blockIdx.x;
    const int cpx  = (gridDim.x * gridDim.y) >> 3;
    const int L    = (flat & 7) * cpx + (flat >> 3);
    bx = L / swz_gy; by = L % swz_gy;      // consecutive L share bx -> B-panel L2 reuse
  } else { bx = blockIdx.x; by = blockIdx.y; }
  const int m0 = by * 256, n0 = bx * 256;
  const size_t bz = blockIdx.z;
  A += bz * (size_t)sA; B += bz * (size_t)sB;

  // staging source map: thread t -> LDS row (t>>2), LDS granule (t&3);
  // source granule = (t&3) ^ ((row>>1)&3) = (t&3) ^ ((t>>3)&3)
  const int srow = t >> 2;                         // 0..127 (call 1: +128)
  const int sgr  = (t & 3) ^ ((t >> 3) & 3);
  const u16* gA = A + (size_t)(m0 + srow) * lda + sgr * 8;
  const u16* gB = B + (size_t)(n0 + srow) * ldb + sgr * 8;
  const size_t a128 = (size_t)128 * lda, b128 = (size_t)128 * ldb;
  const int ldst = wv * 512;                       // wave-uniform elems within 4096-elem call chunk

  const int l15 = ln & 15, lhi = ln >> 4;
  const int wm = (wv >> 2) * 128, wn = (wv & 3) * 64;

  // per-frag swizzled LDS offsets (elems): row r, granule lhi ^ ((r>>1)&3)
  int offA[8], offB[4];
#pragma unroll
  for (int i = 0; i < 8; ++i) {
    const int r = wm + i * 16 + l15;
    offA[i] = r * 32 + ((lhi ^ ((r >> 1) & 3)) << 3);
  }
#pragma unroll
  for (int j = 0; j < 4; ++j) {
    const int r = wn + j * 16 + l15;
    offB[j] = r * 32 + ((lhi ^ ((r >> 1) & 3)) << 3);
  }

  f32x4 acc[8][4] = {};
  const int KT = K >> 5;

  // prologue: stage tiles 0,1,2 (12 per-wave loads); wait tile 0 (8 in flight ok)
#pragma unroll
  for (int pt = 0; pt < 3; ++pt) {
    const u16* _ga = gA + (size_t)pt * 32;
    const u16* _gb = gB + (size_t)pt * 32;
    u16* _la = &lds[pt][0][ldst];
    u16* _lb = &lds[pt][1][ldst];
    gl_lds16(_ga, _la); gl_lds16(_ga + a128, _la + 4096);
    gl_lds16(_gb, _lb); gl_lds16(_gb + b128, _lb + 4096);
  }
  asm volatile("s_waitcnt vmcnt(8)" ::: "memory");
  __builtin_amdgcn_sched_barrier(0);
  __builtin_amdgcn_s_barrier();

  for (int kt = 0; kt < KT; ++kt) {
    const u16* Abuf = &lds[kt & 3][0][0];
    const u16* Bbuf = &lds[kt & 3][1][0];
    const int  nt   = kt + 3;            // tile to stage (into buf last read at kt-1)

    // ---- phase 0: read A frags + B frags 0,1; stage A of tile nt ----
    bf16x8 af[8];
#pragma unroll
    for (int i = 0; i < 8; ++i) af[i] = *(const bf16x8*)&Abuf[offA[i]];
    bf16x8 bf0 = *(const bf16x8*)&Bbuf[offB[0]];
    bf16x8 bf1 = *(const bf16x8*)&Bbuf[offB[1]];
    if (nt < KT) {
      const u16* _ga = gA + (size_t)nt * 32;
      u16* _la = &lds[nt & 3][0][ldst];
      gl_lds16(_ga, _la); gl_lds16(_ga + a128, _la + 4096);
    }
    __builtin_amdgcn_s_barrier();
    __builtin_amdgcn_s_setprio(1);
#pragma unroll
    for (int i = 0; i < 8; ++i) {
      acc[i][0] = __builtin_amdgcn_mfma_f32_16x16x32_bf16(af[i], bf0, acc[i][0], 0, 0, 0);
      acc[i][1] = __builtin_amdgcn_mfma_f32_16x16x32_bf16(af[i], bf1, acc[i][1], 0, 0, 0);
    }
    __builtin_amdgcn_s_setprio(0);
    __builtin_amdgcn_s_barrier();

    // ---- phase 1: read B frags 2,3; stage B of tile nt ----
    bf16x8 bf2 = *(const bf16x8*)&Bbuf[offB[2]];
    bf16x8 bf3 = *(const bf16x8*)&Bbuf[offB[3]];
    if (nt < KT) {
      const u16* _gb = gB + (size_t)nt * 32;
      u16* _lb = &lds[nt & 3][1][ldst];
      gl_lds16(_gb, _lb); gl_lds16(_gb + b128, _lb + 4096);
    }
    __builtin_amdgcn_s_barrier();
    __builtin_amdgcn_s_setprio(1);
#pragma unroll
    for (int i = 0; i < 8; ++i) {
      acc[i][2] = __builtin_amdgcn_mfma_f32_16x16x32_bf16(af[i], bf2, acc[i][2], 0, 0, 0);
      acc[i][3] = __builtin_amdgcn_mfma_f32_16x16x32_bf16(af[i], bf3, acc[i][3], 0, 0, 0);
    }
    __builtin_amdgcn_s_setprio(0);

    // counted wait: ensure tile kt+1 landed; keep up to 2 tiles (8 loads) in flight
    if (kt < KT - 3)       { asm volatile("s_waitcnt vmcnt(8)" ::: "memory"); }
    else if (kt == KT - 3) { asm volatile("s_waitcnt vmcnt(4)" ::: "memory"); }
    else if (kt == KT - 2) { asm volatile("s_waitcnt vmcnt(0)" ::: "memory"); }
    __builtin_amdgcn_sched_barrier(0);
    __builtin_amdgcn_s_barrier();
  }

  // epilogue: frag D row=(lhi*4+r), col=l15 (m89-verified layout)
  const size_t cb = bz * (size_t)sC;
#pragma unroll
  for (int i = 0; i < 8; ++i) {
    const int rg = m0 + wm + i * 16 + lhi * 4;
#pragma unroll
    for (int j = 0; j < 4; ++j) {
      const int cg = n0 + wn + j * 16 + l15;
      const float bsv = bias ? bias[cg] : 0.f;
#pragma unroll
      for (int r = 0; r < 4; ++r) {
        float v = acc[i][j][r] * scale + bsv;
        if (RELU) v = fmaxf(v, 0.f);
        if (F32OUT) ((float*)C)[cb + (size_t)(rg + r) * ldc + cg] = v;
        else        ((u16*)C)[cb + (size_t)(rg + r) * ldc + cg] = f2b(v);
      }
    }
  }
}

// ---------- row softmax with query-row mask, f32 scores -> bf16 attn ----------
__global__ __launch_bounds__(256) void softmax_mask(
    const float* __restrict__ sc, const int* __restrict__ m1,
    const int* __restrict__ m2, u16* __restrict__ attn) {
  __shared__ float red[8];
  const int row = blockIdx.x;            // b*1024 + q
  const int b = row >> 10, q = row & 1023;
  const int mk = (q < 512) ? m1[b * 512 + q] : m2[b * 512 + q - 512];
  f32x4 v = ((const f32x4*)(sc + (size_t)row * 1024))[threadIdx.x];
  if (mk == 0) { v[0] = v[1] = v[2] = v[3] = -INFINITY; }
  float mx = fmaxf(fmaxf(v[0], v[1]), fmaxf(v[2], v[3]));
  mx = wred_max(mx);
  const int ln = threadIdx.x & 63, wv = threadIdx.x >> 6;
  if (ln == 0) red[wv] = mx;
  __syncthreads();
  mx = fmaxf(fmaxf(red[0], red[1]), fmaxf(red[2], red[3]));
  float e0 = __expf(v[0] - mx), e1 = __expf(v[1] - mx);
  float e2 = __expf(v[2] - mx), e3 = __expf(v[3] - mx);
  float s = wred_sum(e0 + e1 + e2 + e3);
  if (ln == 0) red[4 + wv] = s;
  __syncthreads();
  const float inv = 1.f / (red[4] + red[5] + red[6] + red[7]);
  u16x4 o; o[0] = f2b(e0 * inv); o[1] = f2b(e1 * inv); o[2] = f2b(e2 * inv); o[3] = f2b(e3 * inv);
  *(u16x4*)(attn + (size_t)row * 1024 + threadIdx.x * 4) = o;
}

// ---------- final: sigmoid(h2 . W3 + b3), one wave per row ----------
__global__ __launch_bounds__(256) void logits_sigmoid(
    const u16* __restrict__ h2, const float* __restrict__ W3,
    const float* __restrict__ b3, float* __restrict__ out) {
  const int wid = (blockIdx.x * 256 + threadIdx.x) >> 6;  // row
  const int ln = threadIdx.x & 63;
  const u16* r = h2 + (size_t)wid * 1024 + ln * 16;
  u16x8 v0 = *(const u16x8*)r;
  u16x8 v1 = *(const u16x8*)(r + 8);
  const float* w = W3 + ln * 16;
  float s = 0.f;
#pragma unroll
  for (int i = 0; i < 8; ++i) s += b2f(v0[i]) * w[i];
#pragma unroll
  for (int i = 0; i < 8; ++i) s += b2f(v1[i]) * w[8 + i];
#pragma unroll
  for (int o = 32; o > 0; o >>= 1) s += __shfl_down(s, o, 64);
  if (ln == 0) out[wid] = 1.f / (1.f + __expf(-(s + b3[0])));
}

// ---------- launcher ----------
extern "C" void kernel_launch(void* const* d_in, const int* in_sizes, int n_in,
                              void* d_out, int out_size, void* d_ws, size_t ws_size,
                              hipStream_t stream) {
  (void)in_sizes; (void)n_in; (void)out_size; (void)ws_size;
  const float* emb1 = (const float*)d_in[0];
  const float* emb2 = (const float*)d_in[1];
  const int*   mask1 = (const int*)d_in[2];
  const int*   mask2 = (const int*)d_in[3];
  const float* Wq = (const float*)d_in[4];  const float* bq = (const float*)d_in[5];
  const float* Wk = (const float*)d_in[6];  const float* bk = (const float*)d_in[7];
  const float* Wv = (const float*)d_in[8];  const float* bv = (const float*)d_in[9];
  const float* W1 = (const float*)d_in[10]; const float* b1 = (const float*)d_in[11];
  const float* W2 = (const float*)d_in[12]; const float* b2 = (const float*)d_in[13];
  const float* W3 = (const float*)d_in[14]; const float* b3 = (const float*)d_in[15];

  // ws layout (bytes), hand-aliased; peak ~238 MiB
  char* ws = (char*)d_ws;
  u16*  QKV   = (u16*)(ws + 0);            // [16384][3072] bf16; later h1/h2
  u16*  VT    = (u16*)(ws + 100663296);    // [16][1024][1024] bf16
  u16*  XB    = (u16*)(ws + 134217728);    // [16384][1024] bf16; later attn
  u16*  WTQKV = (u16*)(ws + 167772160);    // [3072][1024] bf16
  u16*  W1T   = (u16*)(ws + 174063616);    // [2048][1024] bf16
  u16*  W2T   = (u16*)(ws + 178257920);    // [1024][2048] bf16
  float* SC   = (float*)(ws + 182452224);  // [16][1024][1024] f32; later attended
  float* BF_  = (float*)(ws + 249561088);  // [3072] f32
  u16*  ATTN  = XB;                        // xb dead after QKV GEMM
  u16*  ATT   = (u16*)(ws + 182452224);    // scores dead after softmax
  u16*  H1    = (u16*)(ws + 0);            // QKV dead after PV
  u16*  H2    = (u16*)(ws + 67108864);
  float* out  = (float*)d_out;

  const float SCALE = 0.04419417382415922f;  // 1/sqrt(512)

  concat_convert<<<8192, 256, 0, stream>>>(emb1, emb2, XB);
  transpose_w<<<dim3(16, 16), 256, 0, stream>>>(Wq, 1024, WTQKV, 1024);
  transpose_w<<<dim3(16, 16), 256, 0, stream>>>(Wk, 1024, WTQKV + 1024 * 1024, 1024);
  transpose_w<<<dim3(16, 16), 256, 0, stream>>>(Wv, 1024, WTQKV + 2048 * 1024, 1024);
  transpose_w<<<dim3(32, 16), 256, 0, stream>>>(W1, 2048, W1T, 1024);
  transpose_w<<<dim3(16, 32), 256, 0, stream>>>(W2, 1024, W2T, 2048);
  concat_bias<<<12, 256, 0, stream>>>(bq, bk, bv, BF_);

  // QKV: [16384,1024] x [1024,3072]^T-layout -> bf16 [16384,3072]
  gemm256<0, 0><<<dim3(12, 64, 1), 512, 0, stream>>>(
      XB, 1024, 0, WTQKV, 1024, 0, QKV, 3072, 0, BF_, 1.f, 1024, 64);
  // V^T per batch: [S,D] -> [D,S]
  transpose_v<<<dim3(16, 16, 16), 256, 0, stream>>>(
      QKV + 2048, 3072, 3145728LL, VT, 1024, 1048576LL);
  // scores = scale * Q K^T : batched, f32 out
  gemm256<1, 0><<<dim3(4, 4, 16), 512, 0, stream>>>(
      QKV, 3072, 3145728LL, QKV + 1024, 3072, 3145728LL,
      SC, 1024, 1048576LL, nullptr, SCALE, 1024, 4);
  softmax_mask<<<16384, 256, 0, stream>>>(SC, mask1, mask2, ATTN);
  // attended = attn @ V : batched
  gemm256<0, 0><<<dim3(4, 4, 16), 512, 0, stream>>>(
      ATTN, 1024, 1048576LL, VT, 1024, 1048576LL,
      ATT, 1024, 1048576LL, nullptr, 1.f, 1024, 4);
  // MLP
  gemm256<0, 1><<<dim3(8, 64, 1), 512, 0, stream>>>(
      ATT, 1024, 0, W1T, 1024, 0, H1, 2048, 0, b1, 1.f, 1024, 64);
  gemm256<0, 1><<<dim3(4, 64, 1), 512, 0, stream>>>(
      H1, 2048, 0, W2T, 2048, 0, H2, 1024, 0, b2, 1.f, 2048, 64);
  logits_sigmoid<<<4096, 256, 0, stream>>>(H2, W3, b3, out);
}

// Round 3
// 414.016 us; speedup vs baseline: 1.3874x; 1.0409x over previous
//
#include <hip/hip_runtime.h>
#include <math.h>

#define DEV __device__ __forceinline__

typedef unsigned short u16;
typedef unsigned int   u32;
typedef __bf16 bf16x8 __attribute__((ext_vector_type(8)));
typedef float  f32x4  __attribute__((ext_vector_type(4)));
typedef u16    u16x8  __attribute__((ext_vector_type(8)));
typedef u16    u16x4  __attribute__((ext_vector_type(4)));

// ---------- helpers ----------
DEV u16 f2b(float f) {                 // f32 -> bf16 RNE
  u32 u = __builtin_bit_cast(u32, f);
  u = (u + 0x7FFFu + ((u >> 16) & 1u)) >> 16;
  return (u16)u;
}
DEV float b2f(u16 h) { u32 u = (u32)h << 16; return __builtin_bit_cast(float, u); }

DEV void gl_lds16(const u16* g, u16* l) {  // async global->LDS, 16B/lane (lds ptr wave-uniform)
  __builtin_amdgcn_global_load_lds((const __attribute__((address_space(1))) void*)g,
                                   (__attribute__((address_space(3))) void*)l, 16, 0, 0);
}

DEV float wred_max(float v) {
#pragma unroll
  for (int o = 32; o > 0; o >>= 1) v = fmaxf(v, __shfl_xor(v, o, 64));
  return v;
}
DEV float wred_sum(float v) {
#pragma unroll
  for (int o = 32; o > 0; o >>= 1) v += __shfl_xor(v, o, 64);
  return v;
}

// ---------- concat emb1|emb2 and convert to bf16 ----------
__global__ __launch_bounds__(256) void concat_convert(
    const float* __restrict__ e1, const float* __restrict__ e2, u16* __restrict__ xb) {
  const size_t idx = ((size_t)blockIdx.x * 256 + threadIdx.x) * 8;  // 8 elems/thread
  const int d = (int)(idx & 1023);
  const size_t row = idx >> 10;
  const float* s = (d < 512) ? (e1 + row * 512 + d) : (e2 + row * 512 + (d - 512));
  f32x4 a = *(const f32x4*)s;
  f32x4 b = *(const f32x4*)(s + 4);
  u16x8 o;
  o[0]=f2b(a[0]); o[1]=f2b(a[1]); o[2]=f2b(a[2]); o[3]=f2b(a[3]);
  o[4]=f2b(b[0]); o[5]=f2b(b[1]); o[6]=f2b(b[2]); o[7]=f2b(b[3]);
  *(u16x8*)(xb + idx) = o;
}

// ---------- transpose f32 [K][N] -> bf16 [N][K] (weights) ----------
__global__ __launch_bounds__(256) void transpose_w(
    const float* __restrict__ W, int ldi, u16* __restrict__ WT, int ldo) {
  __shared__ float tile[64][65];
  const int tx = threadIdx.x & 63, ty = threadIdx.x >> 6;
  const int r0 = blockIdx.y * 64, c0 = blockIdx.x * 64;
#pragma unroll
  for (int i = 0; i < 16; ++i)
    tile[ty + 4*i][tx] = W[(size_t)(r0 + ty + 4*i) * ldi + c0 + tx];
  __syncthreads();
#pragma unroll
  for (int i = 0; i < 16; ++i)
    WT[(size_t)(c0 + ty + 4*i) * ldo + r0 + tx] = f2b(tile[tx][ty + 4*i]);
}

// ---------- fused q|k bias (2048) ----------
__global__ void concat_bias(const float* __restrict__ bq, const float* __restrict__ bk,
                            float* __restrict__ o) {
  int i = blockIdx.x * 256 + threadIdx.x;  // 2048 total
  o[i] = (i < 1024) ? bq[i] : bk[i - 1024];
}

// ============================================================================
// 256x256 bf16 GEMM: C = act(scale * A[M,K] x B^T[N,K] + bias)
// BK=32, 4 LDS buffers (128 KiB), stage tile t+3 while computing t -> counted
// vmcnt(8), never drain-0 in main loop. 8 waves (2Mx4N), wave tile 128x64,
// 2 balanced phases/tile x 16 MFMA. LDS XOR swizzle (granule ^= (row>>1)&3)
// on pre-swizzled global source + swizzled ds_read -> 0 bank conflicts (r2).
// 2D-chunked XCD swizzle: XCD k owns a contiguous slab of by-rows (all bx)
// -> concurrent A working set 4MB (L2-resident), B streams with reuse.
// ============================================================================
template<int F32OUT, int RELU, int RBIAS>
__global__ __launch_bounds__(512, 2) void gemm256(
    const u16* __restrict__ A, int lda, long long sA,
    const u16* __restrict__ B, int ldb, long long sB,
    void* __restrict__ C, int ldc, long long sC,
    const float* __restrict__ bias, float scale, int K) {
  __shared__ __align__(16) u16 lds[4][2][8192];   // [buf][A/B][256 rows x 32 cols]

  const int t  = threadIdx.x;
  const int ln = t & 63, wv = t >> 6;

  // --- 2D-chunked bijective XCD swizzle (all grids have nwg % 8 == 0) ---
  int bx, by, bz;
  {
    const int gx = gridDim.x, gy = gridDim.y, gz = gridDim.z;
    const int nwg = gx * gy * gz;
    const int F = (blockIdx.z * gy + blockIdx.y) * gx + blockIdx.x;
    const int q = nwg >> 3;
    const int L = (F & 7) * q + (F >> 3);        // XCD k executes L in [k*q,(k+1)*q)
    if (gz > 1) {
      const int pb = gx * gy;
      bz = L / pb; const int r = L - bz * pb;
      by = r / gx; bx = r - by * gx;             // batch-major: whole batches per XCD
    } else {
      bz = 0;
      const int sh = ((gy & 7) == 0) ? 8 : 4;    // slab height (gy=64 or gy=4)
      const int sw = gx * sh;
      const int sy = L / sw; const int r = L - sy * sw;
      bx = r / sh; by = sy * sh + (r - bx * sh); // slab-major: A-slab resident per XCD
    }
  }
  const int m0 = by * 256, n0 = bx * 256;
  A += (size_t)bz * (size_t)sA; B += (size_t)bz * (size_t)sB;

  // staging source map: thread t -> LDS row (t>>2), LDS granule (t&3);
  // source granule = (t&3) ^ ((row>>1)&3) = (t&3) ^ ((t>>3)&3)
  const int srow = t >> 2;                         // 0..127 (second chunk: +128)
  const int sgr  = (t & 3) ^ ((t >> 3) & 3);
  const u16* gA = A + (size_t)(m0 + srow) * lda + sgr * 8;
  const u16* gB = B + (size_t)(n0 + srow) * ldb + sgr * 8;
  const size_t a128 = (size_t)128 * lda, b128 = (size_t)128 * ldb;
  const int ldst = wv * 512;                       // wave-uniform elems within 4096-elem chunk

  const int l15 = ln & 15, lhi = ln >> 4;
  const int wm = (wv >> 2) * 128, wn = (wv & 3) * 64;

  // per-frag swizzled LDS offsets (elems): row r, granule lhi ^ ((r>>1)&3)
  int offA[8], offB[4];
#pragma unroll
  for (int i = 0; i < 8; ++i) {
    const int r = wm + i * 16 + l15;
    offA[i] = r * 32 + ((lhi ^ ((r >> 1) & 3)) << 3);
  }
#pragma unroll
  for (int j = 0; j < 4; ++j) {
    const int r = wn + j * 16 + l15;
    offB[j] = r * 32 + ((lhi ^ ((r >> 1) & 3)) << 3);
  }

  f32x4 acc[8][4] = {};
  const int KT = K >> 5;

  // prologue: stage tiles 0,1,2 (12 per-wave loads); wait tile 0 (8 in flight ok)
#pragma unroll
  for (int pt = 0; pt < 3; ++pt) {
    const u16* _ga = gA + (size_t)pt * 32;
    const u16* _gb = gB + (size_t)pt * 32;
    u16* _la = &lds[pt][0][ldst];
    u16* _lb = &lds[pt][1][ldst];
    gl_lds16(_ga, _la); gl_lds16(_ga + a128, _la + 4096);
    gl_lds16(_gb, _lb); gl_lds16(_gb + b128, _lb + 4096);
  }
  asm volatile("s_waitcnt vmcnt(8)" ::: "memory");
  __builtin_amdgcn_sched_barrier(0);
  __builtin_amdgcn_s_barrier();

  for (int kt = 0; kt < KT; ++kt) {
    const u16* Abuf = &lds[kt & 3][0][0];
    const u16* Bbuf = &lds[kt & 3][1][0];
    const int  nt   = kt + 3;            // tile to stage (into buf last read at kt-1)

    // ---- phase 0: read A frags 0-3 + all B frags; stage A of tile nt ----
    bf16x8 a0 = *(const bf16x8*)&Abuf[offA[0]];
    bf16x8 a1 = *(const bf16x8*)&Abuf[offA[1]];
    bf16x8 a2 = *(const bf16x8*)&Abuf[offA[2]];
    bf16x8 a3 = *(const bf16x8*)&Abuf[offA[3]];
    bf16x8 b0 = *(const bf16x8*)&Bbuf[offB[0]];
    bf16x8 b1 = *(const bf16x8*)&Bbuf[offB[1]];
    bf16x8 b2 = *(const bf16x8*)&Bbuf[offB[2]];
    bf16x8 b3 = *(const bf16x8*)&Bbuf[offB[3]];
    if (nt < KT) {
      const u16* _ga = gA + (size_t)nt * 32;
      u16* _la = &lds[nt & 3][0][ldst];
      gl_lds16(_ga, _la); gl_lds16(_ga + a128, _la + 4096);
    }
    __builtin_amdgcn_s_barrier();
    __builtin_amdgcn_s_setprio(1);
    acc[0][0] = __builtin_amdgcn_mfma_f32_16x16x32_bf16(a0, b0, acc[0][0], 0, 0, 0);
    acc[0][1] = __builtin_amdgcn_mfma_f32_16x16x32_bf16(a0, b1, acc[0][1], 0, 0, 0);
    acc[0][2] = __builtin_amdgcn_mfma_f32_16x16x32_bf16(a0, b2, acc[0][2], 0, 0, 0);
    acc[0][3] = __builtin_amdgcn_mfma_f32_16x16x32_bf16(a0, b3, acc[0][3], 0, 0, 0);
    acc[1][0] = __builtin_amdgcn_mfma_f32_16x16x32_bf16(a1, b0, acc[1][0], 0, 0, 0);
    acc[1][1] = __builtin_amdgcn_mfma_f32_16x16x32_bf16(a1, b1, acc[1][1], 0, 0, 0);
    acc[1][2] = __builtin_amdgcn_mfma_f32_16x16x32_bf16(a1, b2, acc[1][2], 0, 0, 0);
    acc[1][3] = __builtin_amdgcn_mfma_f32_16x16x32_bf16(a1, b3, acc[1][3], 0, 0, 0);
    acc[2][0] = __builtin_amdgcn_mfma_f32_16x16x32_bf16(a2, b0, acc[2][0], 0, 0, 0);
    acc[2][1] = __builtin_amdgcn_mfma_f32_16x16x32_bf16(a2, b1, acc[2][1], 0, 0, 0);
    acc[2][2] = __builtin_amdgcn_mfma_f32_16x16x32_bf16(a2, b2, acc[2][2], 0, 0, 0);
    acc[2][3] = __builtin_amdgcn_mfma_f32_16x16x32_bf16(a2, b3, acc[2][3], 0, 0, 0);
    acc[3][0] = __builtin_amdgcn_mfma_f32_16x16x32_bf16(a3, b0, acc[3][0], 0, 0, 0);
    acc[3][1] = __builtin_amdgcn_mfma_f32_16x16x32_bf16(a3, b1, acc[3][1], 0, 0, 0);
    acc[3][2] = __builtin_amdgcn_mfma_f32_16x16x32_bf16(a3, b2, acc[3][2], 0, 0, 0);
    acc[3][3] = __builtin_amdgcn_mfma_f32_16x16x32_bf16(a3, b3, acc[3][3], 0, 0, 0);
    __builtin_amdgcn_s_setprio(0);
    __builtin_amdgcn_s_barrier();

    // ---- phase 1: read A frags 4-7; stage B of tile nt ----
    bf16x8 a4 = *(const bf16x8*)&Abuf[offA[4]];
    bf16x8 a5 = *(const bf16x8*)&Abuf[offA[5]];
    bf16x8 a6 = *(const bf16x8*)&Abuf[offA[6]];
    bf16x8 a7 = *(const bf16x8*)&Abuf[offA[7]];
    if (nt < KT) {
      const u16* _gb = gB + (size_t)nt * 32;
      u16* _lb = &lds[nt & 3][1][ldst];
      gl_lds16(_gb, _lb); gl_lds16(_gb + b128, _lb + 4096);
    }
    __builtin_amdgcn_s_barrier();
    __builtin_amdgcn_s_setprio(1);
    acc[4][0] = __builtin_amdgcn_mfma_f32_16x16x32_bf16(a4, b0, acc[4][0], 0, 0, 0);
    acc[4][1] = __builtin_amdgcn_mfma_f32_16x16x32_bf16(a4, b1, acc[4][1], 0, 0, 0);
    acc[4][2] = __builtin_amdgcn_mfma_f32_16x16x32_bf16(a4, b2, acc[4][2], 0, 0, 0);
    acc[4][3] = __builtin_amdgcn_mfma_f32_16x16x32_bf16(a4, b3, acc[4][3], 0, 0, 0);
    acc[5][0] = __builtin_amdgcn_mfma_f32_16x16x32_bf16(a5, b0, acc[5][0], 0, 0, 0);
    acc[5][1] = __builtin_amdgcn_mfma_f32_16x16x32_bf16(a5, b1, acc[5][1], 0, 0, 0);
    acc[5][2] = __builtin_amdgcn_mfma_f32_16x16x32_bf16(a5, b2, acc[5][2], 0, 0, 0);
    acc[5][3] = __builtin_amdgcn_mfma_f32_16x16x32_bf16(a5, b3, acc[5][3], 0, 0, 0);
    acc[6][0] = __builtin_amdgcn_mfma_f32_16x16x32_bf16(a6, b0, acc[6][0], 0, 0, 0);
    acc[6][1] = __builtin_amdgcn_mfma_f32_16x16x32_bf16(a6, b1, acc[6][1], 0, 0, 0);
    acc[6][2] = __builtin_amdgcn_mfma_f32_16x16x32_bf16(a6, b2, acc[6][2], 0, 0, 0);
    acc[6][3] = __builtin_amdgcn_mfma_f32_16x16x32_bf16(a6, b3, acc[6][3], 0, 0, 0);
    acc[7][0] = __builtin_amdgcn_mfma_f32_16x16x32_bf16(a7, b0, acc[7][0], 0, 0, 0);
    acc[7][1] = __builtin_amdgcn_mfma_f32_16x16x32_bf16(a7, b1, acc[7][1], 0, 0, 0);
    acc[7][2] = __builtin_amdgcn_mfma_f32_16x16x32_bf16(a7, b2, acc[7][2], 0, 0, 0);
    acc[7][3] = __builtin_amdgcn_mfma_f32_16x16x32_bf16(a7, b3, acc[7][3], 0, 0, 0);
    __builtin_amdgcn_s_setprio(0);

    // counted wait: ensure tile kt+1 landed; keep up to 2 tiles (8 loads) in flight
    if (kt < KT - 3)       { asm volatile("s_waitcnt vmcnt(8)" ::: "memory"); }
    else if (kt == KT - 3) { asm volatile("s_waitcnt vmcnt(4)" ::: "memory"); }
    else if (kt == KT - 2) { asm volatile("s_waitcnt vmcnt(0)" ::: "memory"); }
    __builtin_amdgcn_sched_barrier(0);
    __builtin_amdgcn_s_barrier();
  }

  // epilogue: frag D row=(lhi*4+r), col=l15 (m89-verified layout)
  const size_t cb = (size_t)bz * (size_t)sC;
#pragma unroll
  for (int i = 0; i < 8; ++i) {
    const int rg = m0 + wm + i * 16 + lhi * 4;
#pragma unroll
    for (int j = 0; j < 4; ++j) {
      const int cg = n0 + wn + j * 16 + l15;
      const float cbv = (!RBIAS && bias) ? bias[cg] : 0.f;
#pragma unroll
      for (int r = 0; r < 4; ++r) {
        float v = acc[i][j][r] * scale + (RBIAS ? bias[rg + r] : cbv);
        if (RELU) v = fmaxf(v, 0.f);
        if (F32OUT) ((float*)C)[cb + (size_t)(rg + r) * ldc + cg] = v;
        else        ((u16*)C)[cb + (size_t)(rg + r) * ldc + cg] = f2b(v);
      }
    }
  }
}

// ---------- row softmax with query-row mask, f32 scores -> bf16 attn ----------
__global__ __launch_bounds__(256) void softmax_mask(
    const float* __restrict__ sc, const int* __restrict__ m1,
    const int* __restrict__ m2, u16* __restrict__ attn) {
  __shared__ float red[8];
  const int row = blockIdx.x;            // b*1024 + q
  const int b = row >> 10, q = row & 1023;
  const int mk = (q < 512) ? m1[b * 512 + q] : m2[b * 512 + q - 512];
  f32x4 v = ((const f32x4*)(sc + (size_t)row * 1024))[threadIdx.x];
  if (mk == 0) { v[0] = v[1] = v[2] = v[3] = -INFINITY; }
  float mx = fmaxf(fmaxf(v[0], v[1]), fmaxf(v[2], v[3]));
  mx = wred_max(mx);
  const int ln = threadIdx.x & 63, wv = threadIdx.x >> 6;
  if (ln == 0) red[wv] = mx;
  __syncthreads();
  mx = fmaxf(fmaxf(red[0], red[1]), fmaxf(red[2], red[3]));
  float e0 = __expf(v[0] - mx), e1 = __expf(v[1] - mx);
  float e2 = __expf(v[2] - mx), e3 = __expf(v[3] - mx);
  float s = wred_sum(e0 + e1 + e2 + e3);
  if (ln == 0) red[4 + wv] = s;
  __syncthreads();
  const float inv = 1.f / (red[4] + red[5] + red[6] + red[7]);
  u16x4 o; o[0] = f2b(e0 * inv); o[1] = f2b(e1 * inv); o[2] = f2b(e2 * inv); o[3] = f2b(e3 * inv);
  *(u16x4*)(attn + (size_t)row * 1024 + threadIdx.x * 4) = o;
}

// ---------- final: sigmoid(h2 . W3 + b3), one wave per row ----------
__global__ __launch_bounds__(256) void logits_sigmoid(
    const u16* __restrict__ h2, const float* __restrict__ W3,
    const float* __restrict__ b3, float* __restrict__ out) {
  const int wid = (blockIdx.x * 256 + threadIdx.x) >> 6;  // row
  const int ln = threadIdx.x & 63;
  const u16* r = h2 + (size_t)wid * 1024 + ln * 16;
  u16x8 v0 = *(const u16x8*)r;
  u16x8 v1 = *(const u16x8*)(r + 8);
  const float* w = W3 + ln * 16;
  float s = 0.f;
#pragma unroll
  for (int i = 0; i < 8; ++i) s += b2f(v0[i]) * w[i];
#pragma unroll
  for (int i = 0; i < 8; ++i) s += b2f(v1[i]) * w[8 + i];
#pragma unroll
  for (int o = 32; o > 0; o >>= 1) s += __shfl_down(s, o, 64);
  if (ln == 0) out[wid] = 1.f / (1.f + __expf(-(s + b3[0])));
}

// ---------- launcher ----------
extern "C" void kernel_launch(void* const* d_in, const int* in_sizes, int n_in,
                              void* d_out, int out_size, void* d_ws, size_t ws_size,
                              hipStream_t stream) {
  (void)in_sizes; (void)n_in; (void)out_size; (void)ws_size;
  const float* emb1 = (const float*)d_in[0];
  const float* emb2 = (const float*)d_in[1];
  const int*   mask1 = (const int*)d_in[2];
  const int*   mask2 = (const int*)d_in[3];
  const float* Wq = (const float*)d_in[4];  const float* bq = (const float*)d_in[5];
  const float* Wk = (const float*)d_in[6];  const float* bk = (const float*)d_in[7];
  const float* Wv = (const float*)d_in[8];  const float* bv = (const float*)d_in[9];
  const float* W1 = (const float*)d_in[10]; const float* b1 = (const float*)d_in[11];
  const float* W2 = (const float*)d_in[12]; const float* b2 = (const float*)d_in[13];
  const float* W3 = (const float*)d_in[14]; const float* b3 = (const float*)d_in[15];

  // ws layout (bytes), hand-aliased; peak ~216 MiB
  char* ws = (char*)d_ws;
  u16*  XB    = (u16*)(ws + 0);            // [16384][1024] bf16; later ATTN
  u16*  QK    = (u16*)(ws + 33554432);     // [16384][2048] bf16 (Q|K); later H1
  u16*  VT    = (u16*)(ws + 100663296);    // [1024][16384] bf16 (V^T, col=b*1024+s); later H2
  float* SC   = (float*)(ws + 134217728);  // [16][1024][1024] f32; later ATT
  u16*  WTQKV = (u16*)(ws + 201326592);    // [3072][1024] bf16 (WqT|WkT|WvT)
  u16*  W1T   = (u16*)(ws + 207618048);    // [2048][1024] bf16
  u16*  W2T   = (u16*)(ws + 211812352);    // [1024][2048] bf16
  float* BF_  = (float*)(ws + 216006656);  // [2048] f32 (bq|bk)
  u16*  ATTN  = XB;                        // XB dead after V-GEMM
  u16*  ATT   = (u16*)(ws + 134217728);    // SC dead after softmax
  u16*  H1    = QK;                        // QK dead after scores GEMM
  u16*  H2    = VT;                        // VT dead after PV GEMM
  float* out  = (float*)d_out;

  const float SCALE = 0.04419417382415922f;  // 1/sqrt(512)

  concat_convert<<<8192, 256, 0, stream>>>(emb1, emb2, XB);
  transpose_w<<<dim3(16, 16), 256, 0, stream>>>(Wq, 1024, WTQKV, 1024);
  transpose_w<<<dim3(16, 16), 256, 0, stream>>>(Wk, 1024, WTQKV + 1024 * 1024, 1024);
  transpose_w<<<dim3(16, 16), 256, 0, stream>>>(Wv, 1024, WTQKV + 2048 * 1024, 1024);
  transpose_w<<<dim3(32, 16), 256, 0, stream>>>(W1, 2048, W1T, 1024);
  transpose_w<<<dim3(16, 32), 256, 0, stream>>>(W2, 1024, W2T, 2048);
  concat_bias<<<8, 256, 0, stream>>>(bq, bk, BF_);

  // Q|K: [16384,1024] x [1024,2048]^T-layout -> bf16 [16384,2048]
  gemm256<0, 0, 0><<<dim3(8, 64, 1), 512, 0, stream>>>(
      XB, 1024, 0, WTQKV, 1024, 0, QK, 2048, 0, BF_, 1.f, 1024);
  // V^T directly: VT[d, b*S+s] = sum_k WvT[d,k] * XB[b*S+s,k] + bv[d] (row bias)
  gemm256<0, 0, 1><<<dim3(64, 4, 1), 512, 0, stream>>>(
      WTQKV + 2048 * 1024, 1024, 0, XB, 1024, 0, VT, 16384, 0, bv, 1.f, 1024);
  // scores = scale * Q K^T : batched, f32 out
  gemm256<1, 0, 0><<<dim3(4, 4, 16), 512, 0, stream>>>(
      QK, 2048, 2097152LL, QK + 1024, 2048, 2097152LL,
      SC, 1024, 1048576LL, nullptr, SCALE, 1024);
  softmax_mask<<<16384, 256, 0, stream>>>(SC, mask1, mask2, ATTN);
  // attended = attn @ V : batched; B-operand = VT rows (batch offset = bz*1024 elems)
  gemm256<0, 0, 0><<<dim3(4, 4, 16), 512, 0, stream>>>(
      ATTN, 1024, 1048576LL, VT, 16384, 1024LL,
      ATT, 1024, 1048576LL, nullptr, 1.f, 1024);
  // MLP
  gemm256<0, 1, 0><<<dim3(8, 64, 1), 512, 0, stream>>>(
      ATT, 1024, 0, W1T, 1024, 0, H1, 2048, 0, b1, 1.f, 1024);
  gemm256<0, 1, 0><<<dim3(4, 64, 1), 512, 0, stream>>>(
      H1, 2048, 0, W2T, 2048, 0, H2, 1024, 0, b2, 1.f, 2048);
  logits_sigmoid<<<4096, 256, 0, stream>>>(H2, W3, b3, out);
}

// Round 4
// 403.951 us; speedup vs baseline: 1.4220x; 1.0249x over previous
//
#include <hip/hip_runtime.h>
#include <math.h>

#define DEV __device__ __forceinline__

typedef unsigned short u16;
typedef unsigned int   u32;
typedef __bf16 bf16x8 __attribute__((ext_vector_type(8)));
typedef float  f32x4  __attribute__((ext_vector_type(4)));
typedef u16    u16x8  __attribute__((ext_vector_type(8)));
typedef u16    u16x4  __attribute__((ext_vector_type(4)));

// ---------- helpers ----------
DEV u16 f2b(float f) {                 // f32 -> bf16 RNE
  u32 u = __builtin_bit_cast(u32, f);
  u = (u + 0x7FFFu + ((u >> 16) & 1u)) >> 16;
  return (u16)u;
}
DEV float b2f(u16 h) { u32 u = (u32)h << 16; return __builtin_bit_cast(float, u); }

DEV void gl_lds16(const u16* g, u16* l) {  // async global->LDS, 16B/lane (lds ptr wave-uniform)
  __builtin_amdgcn_global_load_lds((const __attribute__((address_space(1))) void*)g,
                                   (__attribute__((address_space(3))) void*)l, 16, 0, 0);
}

DEV float wred_max(float v) {
#pragma unroll
  for (int o = 32; o > 0; o >>= 1) v = fmaxf(v, __shfl_xor(v, o, 64));
  return v;
}
DEV float wred_sum(float v) {
#pragma unroll
  for (int o = 32; o > 0; o >>= 1) v += __shfl_xor(v, o, 64);
  return v;
}

// ---------- concat emb1|emb2 and convert to bf16 ----------
__global__ __launch_bounds__(256) void concat_convert(
    const float* __restrict__ e1, const float* __restrict__ e2, u16* __restrict__ xb) {
  const size_t idx = ((size_t)blockIdx.x * 256 + threadIdx.x) * 8;  // 8 elems/thread
  const int d = (int)(idx & 1023);
  const size_t row = idx >> 10;
  const float* s = (d < 512) ? (e1 + row * 512 + d) : (e2 + row * 512 + (d - 512));
  f32x4 a = *(const f32x4*)s;
  f32x4 b = *(const f32x4*)(s + 4);
  u16x8 o;
  o[0]=f2b(a[0]); o[1]=f2b(a[1]); o[2]=f2b(a[2]); o[3]=f2b(a[3]);
  o[4]=f2b(b[0]); o[5]=f2b(b[1]); o[6]=f2b(b[2]); o[7]=f2b(b[3]);
  *(u16x8*)(xb + idx) = o;
}

// ---------- transpose f32 [K][N] -> bf16 [N][K] (weights) ----------
__global__ __launch_bounds__(256) void transpose_w(
    const float* __restrict__ W, int ldi, u16* __restrict__ WT, int ldo) {
  __shared__ float tile[64][65];
  const int tx = threadIdx.x & 63, ty = threadIdx.x >> 6;
  const int r0 = blockIdx.y * 64, c0 = blockIdx.x * 64;
#pragma unroll
  for (int i = 0; i < 16; ++i)
    tile[ty + 4*i][tx] = W[(size_t)(r0 + ty + 4*i) * ldi + c0 + tx];
  __syncthreads();
#pragma unroll
  for (int i = 0; i < 16; ++i)
    WT[(size_t)(c0 + ty + 4*i) * ldo + r0 + tx] = f2b(tile[tx][ty + 4*i]);
}

// ---------- fused q|k bias (2048) ----------
__global__ void concat_bias(const float* __restrict__ bq, const float* __restrict__ bk,
                            float* __restrict__ o) {
  int i = blockIdx.x * 256 + threadIdx.x;  // 2048 total
  o[i] = (i < 1024) ? bq[i] : bk[i - 1024];
}

// ============================================================================
// 256x256 bf16 GEMM: C = act(scale * A[M,K] x B^T[N,K] + bias)
// BK=32, 4 LDS buffers (128 KiB). ONE barrier per K-tile (AITER structure:
// ~32 MFMA per barrier, counted vmcnt never 0 mid-loop). Race-freedom:
//  - all 12 ds_reads of buf[kt&3] are lgkm-consumed inside body kt, so the
//    end-barrier of kt proves every wave is done with buf[kt&3];
//  - gl_lds for tile kt+3 -> buf[(kt-1)&3] issues in body kt, i.e. after the
//    end-barrier of kt-1, whose reads completed within body kt-1;
//  - vmcnt(8) at end of body kt drains tile kt+1 (oldest 4 loads), so body
//    kt+1's reads (after the barrier) see landed data.
// LDS XOR swizzle (granule ^= (row>>1)&3) on pre-swizzled global source +
// swizzled ds_read -> 0 bank conflicts (verified r2). 2D-chunked XCD swizzle.
// ============================================================================
template<int F32OUT, int RELU, int RBIAS>
__global__ __launch_bounds__(512, 2) void gemm256(
    const u16* __restrict__ A, int lda, long long sA,
    const u16* __restrict__ B, int ldb, long long sB,
    void* __restrict__ C, int ldc, long long sC,
    const float* __restrict__ bias, float scale, int K) {
  __shared__ __align__(16) u16 lds[4][2][8192];   // [buf][A/B][256 rows x 32 cols]

  const int t  = threadIdx.x;
  const int ln = t & 63, wv = t >> 6;

  // --- 2D-chunked bijective XCD swizzle (all grids have nwg % 8 == 0) ---
  int bx, by, bz;
  {
    const int gx = gridDim.x, gy = gridDim.y, gz = gridDim.z;
    const int nwg = gx * gy * gz;
    const int F = (blockIdx.z * gy + blockIdx.y) * gx + blockIdx.x;
    const int q = nwg >> 3;
    const int L = (F & 7) * q + (F >> 3);        // XCD k executes L in [k*q,(k+1)*q)
    if (gz > 1) {
      const int pb = gx * gy;
      bz = L / pb; const int r = L - bz * pb;
      by = r / gx; bx = r - by * gx;             // batch-major: whole batches per XCD
    } else {
      bz = 0;
      const int sh = ((gy & 7) == 0) ? 8 : 4;    // slab height (gy=64 or gy=4)
      const int sw = gx * sh;
      const int sy = L / sw; const int r = L - sy * sw;
      bx = r / sh; by = sy * sh + (r - bx * sh); // slab-major: A-slab resident per XCD
    }
  }
  const int m0 = by * 256, n0 = bx * 256;
  A += (size_t)bz * (size_t)sA; B += (size_t)bz * (size_t)sB;

  // staging source map: thread t -> LDS row (t>>2), LDS granule (t&3);
  // source granule = (t&3) ^ ((row>>1)&3) = (t&3) ^ ((t>>3)&3)
  const int srow = t >> 2;                         // 0..127 (second chunk: +128)
  const int sgr  = (t & 3) ^ ((t >> 3) & 3);
  const u16* gA = A + (size_t)(m0 + srow) * lda + sgr * 8;
  const u16* gB = B + (size_t)(n0 + srow) * ldb + sgr * 8;
  const size_t a128 = (size_t)128 * lda, b128 = (size_t)128 * ldb;
  const int ldst = wv * 512;                       // wave-uniform elems within 4096-elem chunk

  const int l15 = ln & 15, lhi = ln >> 4;
  const int wm = (wv >> 2) * 128, wn = (wv & 3) * 64;

  // per-frag swizzled LDS offsets (elems): row r, granule lhi ^ ((r>>1)&3)
  int offA[8], offB[4];
#pragma unroll
  for (int i = 0; i < 8; ++i) {
    const int r = wm + i * 16 + l15;
    offA[i] = r * 32 + ((lhi ^ ((r >> 1) & 3)) << 3);
  }
#pragma unroll
  for (int j = 0; j < 4; ++j) {
    const int r = wn + j * 16 + l15;
    offB[j] = r * 32 + ((lhi ^ ((r >> 1) & 3)) << 3);
  }

  f32x4 acc[8][4] = {};
  const int KT = K >> 5;

  // prologue: stage tiles 0,1,2 (12 per-wave loads); wait tile 0 (8 in flight ok)
#pragma unroll
  for (int pt = 0; pt < 3; ++pt) {
    const u16* _ga = gA + (size_t)pt * 32;
    const u16* _gb = gB + (size_t)pt * 32;
    u16* _la = &lds[pt][0][ldst];
    u16* _lb = &lds[pt][1][ldst];
    gl_lds16(_ga, _la); gl_lds16(_ga + a128, _la + 4096);
    gl_lds16(_gb, _lb); gl_lds16(_gb + b128, _lb + 4096);
  }
  asm volatile("s_waitcnt vmcnt(8)" ::: "memory");
  __builtin_amdgcn_sched_barrier(0);
  __builtin_amdgcn_s_barrier();

  for (int kt = 0; kt < KT; ++kt) {
    const u16* Abuf = &lds[kt & 3][0][0];
    const u16* Bbuf = &lds[kt & 3][1][0];
    const int  nt   = kt + 3;            // tile to stage (into buf last read at kt-1)

    // stage tile nt (buf[(kt-1)&3], safe: its reads completed inside body kt-1)
    if (nt < KT) {
      const u16* _ga = gA + (size_t)nt * 32;
      const u16* _gb = gB + (size_t)nt * 32;
      u16* _la = &lds[nt & 3][0][ldst];
      u16* _lb = &lds[nt & 3][1][ldst];
      gl_lds16(_ga, _la); gl_lds16(_ga + a128, _la + 4096);
      gl_lds16(_gb, _lb); gl_lds16(_gb + b128, _lb + 4096);
    }

    // all 12 frag reads; first 8 feed cluster 1, a4-7 stay in flight under it
    bf16x8 a0 = *(const bf16x8*)&Abuf[offA[0]];
    bf16x8 a1 = *(const bf16x8*)&Abuf[offA[1]];
    bf16x8 a2 = *(const bf16x8*)&Abuf[offA[2]];
    bf16x8 a3 = *(const bf16x8*)&Abuf[offA[3]];
    bf16x8 b0 = *(const bf16x8*)&Bbuf[offB[0]];
    bf16x8 b1 = *(const bf16x8*)&Bbuf[offB[1]];
    bf16x8 b2 = *(const bf16x8*)&Bbuf[offB[2]];
    bf16x8 b3 = *(const bf16x8*)&Bbuf[offB[3]];
    bf16x8 a4 = *(const bf16x8*)&Abuf[offA[4]];
    bf16x8 a5 = *(const bf16x8*)&Abuf[offA[5]];
    bf16x8 a6 = *(const bf16x8*)&Abuf[offA[6]];
    bf16x8 a7 = *(const bf16x8*)&Abuf[offA[7]];

    __builtin_amdgcn_s_setprio(1);
    acc[0][0] = __builtin_amdgcn_mfma_f32_16x16x32_bf16(a0, b0, acc[0][0], 0, 0, 0);
    acc[0][1] = __builtin_amdgcn_mfma_f32_16x16x32_bf16(a0, b1, acc[0][1], 0, 0, 0);
    acc[0][2] = __builtin_amdgcn_mfma_f32_16x16x32_bf16(a0, b2, acc[0][2], 0, 0, 0);
    acc[0][3] = __builtin_amdgcn_mfma_f32_16x16x32_bf16(a0, b3, acc[0][3], 0, 0, 0);
    acc[1][0] = __builtin_amdgcn_mfma_f32_16x16x32_bf16(a1, b0, acc[1][0], 0, 0, 0);
    acc[1][1] = __builtin_amdgcn_mfma_f32_16x16x32_bf16(a1, b1, acc[1][1], 0, 0, 0);
    acc[1][2] = __builtin_amdgcn_mfma_f32_16x16x32_bf16(a1, b2, acc[1][2], 0, 0, 0);
    acc[1][3] = __builtin_amdgcn_mfma_f32_16x16x32_bf16(a1, b3, acc[1][3], 0, 0, 0);
    acc[2][0] = __builtin_amdgcn_mfma_f32_16x16x32_bf16(a2, b0, acc[2][0], 0, 0, 0);
    acc[2][1] = __builtin_amdgcn_mfma_f32_16x16x32_bf16(a2, b1, acc[2][1], 0, 0, 0);
    acc[2][2] = __builtin_amdgcn_mfma_f32_16x16x32_bf16(a2, b2, acc[2][2], 0, 0, 0);
    acc[2][3] = __builtin_amdgcn_mfma_f32_16x16x32_bf16(a2, b3, acc[2][3], 0, 0, 0);
    acc[3][0] = __builtin_amdgcn_mfma_f32_16x16x32_bf16(a3, b0, acc[3][0], 0, 0, 0);
    acc[3][1] = __builtin_amdgcn_mfma_f32_16x16x32_bf16(a3, b1, acc[3][1], 0, 0, 0);
    acc[3][2] = __builtin_amdgcn_mfma_f32_16x16x32_bf16(a3, b2, acc[3][2], 0, 0, 0);
    acc[3][3] = __builtin_amdgcn_mfma_f32_16x16x32_bf16(a3, b3, acc[3][3], 0, 0, 0);
    acc[4][0] = __builtin_amdgcn_mfma_f32_16x16x32_bf16(a4, b0, acc[4][0], 0, 0, 0);
    acc[4][1] = __builtin_amdgcn_mfma_f32_16x16x32_bf16(a4, b1, acc[4][1], 0, 0, 0);
    acc[4][2] = __builtin_amdgcn_mfma_f32_16x16x32_bf16(a4, b2, acc[4][2], 0, 0, 0);
    acc[4][3] = __builtin_amdgcn_mfma_f32_16x16x32_bf16(a4, b3, acc[4][3], 0, 0, 0);
    acc[5][0] = __builtin_amdgcn_mfma_f32_16x16x32_bf16(a5, b0, acc[5][0], 0, 0, 0);
    acc[5][1] = __builtin_amdgcn_mfma_f32_16x16x32_bf16(a5, b1, acc[5][1], 0, 0, 0);
    acc[5][2] = __builtin_amdgcn_mfma_f32_16x16x32_bf16(a5, b2, acc[5][2], 0, 0, 0);
    acc[5][3] = __builtin_amdgcn_mfma_f32_16x16x32_bf16(a5, b3, acc[5][3], 0, 0, 0);
    acc[6][0] = __builtin_amdgcn_mfma_f32_16x16x32_bf16(a6, b0, acc[6][0], 0, 0, 0);
    acc[6][1] = __builtin_amdgcn_mfma_f32_16x16x32_bf16(a6, b1, acc[6][1], 0, 0, 0);
    acc[6][2] = __builtin_amdgcn_mfma_f32_16x16x32_bf16(a6, b2, acc[6][2], 0, 0, 0);
    acc[6][3] = __builtin_amdgcn_mfma_f32_16x16x32_bf16(a6, b3, acc[6][3], 0, 0, 0);
    acc[7][0] = __builtin_amdgcn_mfma_f32_16x16x32_bf16(a7, b0, acc[7][0], 0, 0, 0);
    acc[7][1] = __builtin_amdgcn_mfma_f32_16x16x32_bf16(a7, b1, acc[7][1], 0, 0, 0);
    acc[7][2] = __builtin_amdgcn_mfma_f32_16x16x32_bf16(a7, b2, acc[7][2], 0, 0, 0);
    acc[7][3] = __builtin_amdgcn_mfma_f32_16x16x32_bf16(a7, b3, acc[7][3], 0, 0, 0);
    __builtin_amdgcn_s_setprio(0);

    // counted wait: tile kt+1 landed; keep up to 2 tiles (8 loads) in flight
    if (kt < KT - 3)       { asm volatile("s_waitcnt vmcnt(8)" ::: "memory"); }
    else if (kt == KT - 3) { asm volatile("s_waitcnt vmcnt(4)" ::: "memory"); }
    else if (kt == KT - 2) { asm volatile("s_waitcnt vmcnt(0)" ::: "memory"); }
    __builtin_amdgcn_sched_barrier(0);
    __builtin_amdgcn_s_barrier();     // single barrier per K-tile
  }

  // epilogue: frag D row=(lhi*4+r), col=l15 (m89-verified layout)
  const size_t cb = (size_t)bz * (size_t)sC;
#pragma unroll
  for (int i = 0; i < 8; ++i) {
    const int rg = m0 + wm + i * 16 + lhi * 4;
#pragma unroll
    for (int j = 0; j < 4; ++j) {
      const int cg = n0 + wn + j * 16 + l15;
      const float cbv = (!RBIAS && bias) ? bias[cg] : 0.f;
#pragma unroll
      for (int r = 0; r < 4; ++r) {
        float v = acc[i][j][r] * scale + (RBIAS ? bias[rg + r] : cbv);
        if (RELU) v = fmaxf(v, 0.f);
        if (F32OUT) ((float*)C)[cb + (size_t)(rg + r) * ldc + cg] = v;
        else        ((u16*)C)[cb + (size_t)(rg + r) * ldc + cg] = f2b(v);
      }
    }
  }
}

// ---------- row softmax with query-row mask, f32 scores -> bf16 attn ----------
__global__ __launch_bounds__(256) void softmax_mask(
    const float* __restrict__ sc, const int* __restrict__ m1,
    const int* __restrict__ m2, u16* __restrict__ attn) {
  __shared__ float red[8];
  const int row = blockIdx.x;            // b*1024 + q
  const int b = row >> 10, q = row & 1023;
  const int mk = (q < 512) ? m1[b * 512 + q] : m2[b * 512 + q - 512];
  f32x4 v = ((const f32x4*)(sc + (size_t)row * 1024))[threadIdx.x];
  if (mk == 0) { v[0] = v[1] = v[2] = v[3] = -INFINITY; }
  float mx = fmaxf(fmaxf(v[0], v[1]), fmaxf(v[2], v[3]));
  mx = wred_max(mx);
  const int ln = threadIdx.x & 63, wv = threadIdx.x >> 6;
  if (ln == 0) red[wv] = mx;
  __syncthreads();
  mx = fmaxf(fmaxf(red[0], red[1]), fmaxf(red[2], red[3]));
  float e0 = __expf(v[0] - mx), e1 = __expf(v[1] - mx);
  float e2 = __expf(v[2] - mx), e3 = __expf(v[3] - mx);
  float s = wred_sum(e0 + e1 + e2 + e3);
  if (ln == 0) red[4 + wv] = s;
  __syncthreads();
  const float inv = 1.f / (red[4] + red[5] + red[6] + red[7]);
  u16x4 o; o[0] = f2b(e0 * inv); o[1] = f2b(e1 * inv); o[2] = f2b(e2 * inv); o[3] = f2b(e3 * inv);
  *(u16x4*)(attn + (size_t)row * 1024 + threadIdx.x * 4) = o;
}

// ---------- final: sigmoid(h2 . W3 + b3), one wave per row ----------
__global__ __launch_bounds__(256) void logits_sigmoid(
    const u16* __restrict__ h2, const float* __restrict__ W3,
    const float* __restrict__ b3, float* __restrict__ out) {
  const int wid = (blockIdx.x * 256 + threadIdx.x) >> 6;  // row
  const int ln = threadIdx.x & 63;
  const u16* r = h2 + (size_t)wid * 1024 + ln * 16;
  u16x8 v0 = *(const u16x8*)r;
  u16x8 v1 = *(const u16x8*)(r + 8);
  const float* w = W3 + ln * 16;
  float s = 0.f;
#pragma unroll
  for (int i = 0; i < 8; ++i) s += b2f(v0[i]) * w[i];
#pragma unroll
  for (int i = 0; i < 8; ++i) s += b2f(v1[i]) * w[8 + i];
#pragma unroll
  for (int o = 32; o > 0; o >>= 1) s += __shfl_down(s, o, 64);
  if (ln == 0) out[wid] = 1.f / (1.f + __expf(-(s + b3[0])));
}

// ---------- launcher ----------
extern "C" void kernel_launch(void* const* d_in, const int* in_sizes, int n_in,
                              void* d_out, int out_size, void* d_ws, size_t ws_size,
                              hipStream_t stream) {
  (void)in_sizes; (void)n_in; (void)out_size; (void)ws_size;
  const float* emb1 = (const float*)d_in[0];
  const float* emb2 = (const float*)d_in[1];
  const int*   mask1 = (const int*)d_in[2];
  const int*   mask2 = (const int*)d_in[3];
  const float* Wq = (const float*)d_in[4];  const float* bq = (const float*)d_in[5];
  const float* Wk = (const float*)d_in[6];  const float* bk = (const float*)d_in[7];
  const float* Wv = (const float*)d_in[8];  const float* bv = (const float*)d_in[9];
  const float* W1 = (const float*)d_in[10]; const float* b1 = (const float*)d_in[11];
  const float* W2 = (const float*)d_in[12]; const float* b2 = (const float*)d_in[13];
  const float* W3 = (const float*)d_in[14]; const float* b3 = (const float*)d_in[15];

  // ws layout (bytes), hand-aliased; peak ~216 MiB
  char* ws = (char*)d_ws;
  u16*  XB    = (u16*)(ws + 0);            // [16384][1024] bf16; later ATTN
  u16*  QK    = (u16*)(ws + 33554432);     // [16384][2048] bf16 (Q|K); later H1
  u16*  VT    = (u16*)(ws + 100663296);    // [1024][16384] bf16 (V^T); later H2
  float* SC   = (float*)(ws + 134217728);  // [16][1024][1024] f32; later ATT
  u16*  WTQKV = (u16*)(ws + 201326592);    // [3072][1024] bf16 (WqT|WkT|WvT)
  u16*  W1T   = (u16*)(ws + 207618048);    // [2048][1024] bf16
  u16*  W2T   = (u16*)(ws + 211812352);    // [1024][2048] bf16
  float* BF_  = (float*)(ws + 216006656);  // [2048] f32 (bq|bk)
  u16*  ATTN  = XB;                        // XB dead after V-GEMM
  u16*  ATT   = (u16*)(ws + 134217728);    // SC dead after softmax
  u16*  H1    = QK;                        // QK dead after scores GEMM
  u16*  H2    = VT;                        // VT dead after PV GEMM
  float* out  = (float*)d_out;

  const float SCALE = 0.04419417382415922f;  // 1/sqrt(512)

  concat_convert<<<8192, 256, 0, stream>>>(emb1, emb2, XB);
  transpose_w<<<dim3(16, 16), 256, 0, stream>>>(Wq, 1024, WTQKV, 1024);
  transpose_w<<<dim3(16, 16), 256, 0, stream>>>(Wk, 1024, WTQKV + 1024 * 1024, 1024);
  transpose_w<<<dim3(16, 16), 256, 0, stream>>>(Wv, 1024, WTQKV + 2048 * 1024, 1024);
  transpose_w<<<dim3(32, 16), 256, 0, stream>>>(W1, 2048, W1T, 1024);
  transpose_w<<<dim3(16, 32), 256, 0, stream>>>(W2, 1024, W2T, 2048);
  concat_bias<<<8, 256, 0, stream>>>(bq, bk, BF_);

  // Q|K: [16384,1024] x [1024,2048]^T-layout -> bf16 [16384,2048]
  gemm256<0, 0, 0><<<dim3(8, 64, 1), 512, 0, stream>>>(
      XB, 1024, 0, WTQKV, 1024, 0, QK, 2048, 0, BF_, 1.f, 1024);
  // V^T directly: VT[d, b*S+s] = sum_k WvT[d,k] * XB[b*S+s,k] + bv[d] (row bias)
  gemm256<0, 0, 1><<<dim3(64, 4, 1), 512, 0, stream>>>(
      WTQKV + 2048 * 1024, 1024, 0, XB, 1024, 0, VT, 16384, 0, bv, 1.f, 1024);
  // scores = scale * Q K^T : batched, f32 out
  gemm256<1, 0, 0><<<dim3(4, 4, 16), 512, 0, stream>>>(
      QK, 2048, 2097152LL, QK + 1024, 2048, 2097152LL,
      SC, 1024, 1048576LL, nullptr, SCALE, 1024);
  softmax_mask<<<16384, 256, 0, stream>>>(SC, mask1, mask2, ATTN);
  // attended = attn @ V : batched; B-operand = VT rows (batch offset = bz*1024 elems)
  gemm256<0, 0, 0><<<dim3(4, 4, 16), 512, 0, stream>>>(
      ATTN, 1024, 1048576LL, VT, 16384, 1024LL,
      ATT, 1024, 1048576LL, nullptr, 1.f, 1024);
  // MLP
  gemm256<0, 1, 0><<<dim3(8, 64, 1), 512, 0, stream>>>(
      ATT, 1024, 0, W1T, 1024, 0, H1, 2048, 0, b1, 1.f, 1024);
  gemm256<0, 1, 0><<<dim3(4, 64, 1), 512, 0, stream>>>(
      H1, 2048, 0, W2T, 2048, 0, H2, 1024, 0, b2, 1.f, 2048);
  logits_sigmoid<<<4096, 256, 0, stream>>>(H2, W3, b3, out);
}